// Round 9
// baseline (87.397 us; speedup 1.0000x reference)
//
#include <hip/hip_runtime.h>

#define NB 16
#define TT 6000
#define HH 256
#define CC 105
#define MIN_GAP_ 19
#define REF_GAP_ 9

using short8  = __attribute__((ext_vector_type(8))) short;
using short4v = __attribute__((ext_vector_type(4))) short;
using f32x4   = __attribute__((ext_vector_type(4))) float;

static __device__ __forceinline__ short f2bf(float x) {
  unsigned u = __builtin_bit_cast(unsigned, x);
  unsigned r = (u + 0x7FFFu + ((u >> 16) & 1u)) >> 16;   // RNE
  return (short)r;
}

// ---- one-time W (channels 1..104) f32 -> bf16, zero-padded to 112 rows ----
__global__ __launch_bounds__(256) void wconv_kernel(
    const float* __restrict__ W, unsigned short* __restrict__ Wb) {
  const int idx = blockIdx.x * 256 + threadIdx.x;   // 0..28671 (112*256)
  const int c = idx >> 8, k = idx & 255;
  const float v = (c < CC - 1) ? W[(size_t)(c + 1) * HH + k] : 0.f;
  Wb[idx] = (unsigned short)f2bf(v);
}

// ---- GEMM: BOTH operands in LDS under the 2-blocks/CU threshold.
// BM=48 (A bf16 24KB) + B 104 rows (53.25KB) = 77.8KB LDS -> 2 blocks/CU.
// 6 waves = 3 row-groups x 2 channel-groups. XCD-swizzled blockIdx.
#define BMR 48
#define NGB 2000   // 96000/48

__global__ __launch_bounds__(384, 3) void gemm_mfma(
    const float* __restrict__ feat, const float* __restrict__ W,
    const float* __restrict__ bias, const unsigned short* __restrict__ Wb,
    float* __restrict__ out0, float* __restrict__ out1) {
  __shared__ __align__(16) unsigned char lds[77824];
  unsigned short* bS = (unsigned short*)lds;              // 104 rows x 512B
  unsigned short* aS = (unsigned short*)(lds + 53248);    // 48 rows x 512B

  const int tid  = threadIdx.x;
  const int wid  = tid >> 6;        // wave 0..5
  const int lane = tid & 63;
  // XCD-aware bijective swizzle (2000 % 8 == 0)
  const int bid  = (blockIdx.x & 7) * (NGB / 8) + (blockIdx.x >> 3);
  const int row0 = bid * BMR;

  // ---- issue B stage loads (104*512B = 3328 x 16B chunks over 384 thr) ----
  short8 breg[9];
#pragma unroll
  for (int i = 0; i < 9; i++) {
    const int c16 = tid + i * 384;
    if (c16 < 3328)
      breg[i] = *reinterpret_cast<const short8*>(Wb + ((size_t)c16 << 3));
  }

  // ---- issue A stage loads (8 full rows per wave, 1KB coalesced each) ----
  const float4 w0 = *reinterpret_cast<const float4*>(W + lane * 4);
  float4 areg[8];
#pragma unroll
  for (int i = 0; i < 8; i++) {
    const int lrow = i * 6 + wid;
    areg[i] = *reinterpret_cast<const float4*>(
        feat + (size_t)(row0 + lrow) * HH + lane * 4);
  }

  // ---- B: swizzled LDS writes ----
#pragma unroll
  for (int i = 0; i < 9; i++) {
    const int c16 = tid + i * 384;
    if (c16 < 3328) {
      const int byte = c16 << 4;
      const int brow = byte >> 9;
      const int boff = byte & 511;
      *reinterpret_cast<short8*>(
          (char*)bS + (brow << 9) + (boff ^ ((brow & 7) << 4))) = breg[i];
    }
  }

  // ---- A: ch0 dot (wave reduce, round-7 order) + bf16 + swizzled write ----
#pragma unroll
  for (int i = 0; i < 8; i++) {
    const int lrow = i * 6 + wid;
    const float4 a = areg[i];
    float p = a.x * w0.x;
    p = fmaf(a.y, w0.y, p); p = fmaf(a.z, w0.z, p); p = fmaf(a.w, w0.w, p);
#pragma unroll
    for (int off = 1; off < 64; off <<= 1) p += __shfl_xor(p, off);
    if (lane == 0)
      out0[row0 + lrow] = fminf(fmaxf(p + bias[0], -16.f), 16.f);
    short4v bf;
    bf[0] = f2bf(a.x); bf[1] = f2bf(a.y); bf[2] = f2bf(a.z); bf[3] = f2bf(a.w);
    const int dst = (lrow << 9) + ((lane * 8) ^ ((lrow & 7) << 4));
    *reinterpret_cast<short4v*>((char*)aS + dst) = bf;
  }
  __syncthreads();

  // ---- MFMA sweep: pure LDS operands ----
  const int rg = wid >> 1;          // row-group 0..2
  const int cg = wid & 1;           // 0: n=0..3, 1: n=4..6
  const int rl = lane & 15;
  const int kg = lane >> 4;
  const int xr = (rl & 7) << 4;
  const char* abase = (const char*)aS + ((rg * 16 + rl) << 9);
  const int ngbase = cg * 4;

  f32x4 acc[4];
#pragma unroll
  for (int n = 0; n < 4; n++) acc[n] = (f32x4){0.f, 0.f, 0.f, 0.f};

#pragma unroll
  for (int ks = 0; ks < 8; ks++) {
    const int slot = (ks * 64 + kg * 16) ^ xr;
    const short8 av = *reinterpret_cast<const short8*>(abase + slot);
#pragma unroll
    for (int n = 0; n < 4; n++) {
      const int ng = ngbase + n;
      if (ng < 7) {
        const short8 bv = *reinterpret_cast<const short8*>(
            (const char*)bS + (((ng * 16 + rl) << 9) + slot));
        acc[n] = __builtin_amdgcn_mfma_f32_16x16x32_bf16(av, bv, acc[n], 0, 0, 0);
      }
    }
  }

  // D layout: col = lane&15, row = (lane>>4)*4 + reg  [m89]
  const int rbase = row0 + rg * 16 + kg * 4;
#pragma unroll
  for (int n = 0; n < 4; n++) {
    const int ng = ngbase + n;
    if (ng < 7) {
      const int c = ng * 16 + rl;
      if (c < CC - 1) {
        const float bb = bias[c + 1];
#pragma unroll
        for (int r = 0; r < 4; r++)
          out1[(size_t)(rbase + r) * (CC - 1) + c] = acc[n][r] + bb;
      }
    }
  }
}

// ---- phase: bitwise run detect + chunk-speculative merge + parallel p2 ----
#define NW 192
#define NW_LAST 187
#define CHUNK 32
#define NCLS 19
#define MAXRUNS 3072
#define MAXCH 96

__global__ __launch_bounds__(512) void phase_kernel(
    const float* __restrict__ bd_logits,
    const int* __restrict__ word_bd,
    const float* __restrict__ non_padding,
    float* __restrict__ out2) {
  __shared__ __align__(16) float lbuf[TT];
  __shared__ unsigned char wbuf[TT];
  __shared__ int res[TT];
  __shared__ unsigned bdbits[NW];
  __shared__ int runIdx[MAXRUNS];
  __shared__ int outLast[MAXCH][NCLS + 1];
  __shared__ int chP0[MAXCH];
  __shared__ int inL[MAXCH + 1];
  __shared__ int wsum[8];
  __shared__ int wbase[8];
  __shared__ int L_sh, nruns_sh;

  const int b = blockIdx.x;
  const int tid = threadIdx.x;
  const int lane = tid & 63;
  const int wid = tid >> 6;
  if (tid == 0) L_sh = 0;
  __syncthreads();

  int cnt_np = 0;
#pragma unroll
  for (int k = 0; k < 12; k++) {
    const int j = k * 512 + tid;
    bool pred = false;
    if (j < TT) {
      const float l = bd_logits[(size_t)b * TT + j];
      lbuf[j] = l;
      pred = l > 0.f;
      wbuf[j] = (unsigned char)word_bd[(size_t)b * TT + j];
      res[j] = 0;
      cnt_np += (non_padding[(size_t)b * TT + j] != 0.f) ? 1 : 0;
    }
    const unsigned long long m = __ballot(pred);
    if (lane == 0) {
      const int w0 = (k * 512 + (tid & ~63)) >> 5;
      bdbits[w0]     = (unsigned)m;
      bdbits[w0 + 1] = (unsigned)(m >> 32);
    }
  }
#pragma unroll
  for (int off = 32; off; off >>= 1) cnt_np += __shfl_xor(cnt_np, off);
  if (lane == 0) atomicAdd(&L_sh, cnt_np);
  __syncthreads();

  int cnt = 0;
  unsigned ends = 0;
  if (tid < NW) {
    const unsigned cur = bdbits[tid];
    const unsigned pb = tid ? (bdbits[tid - 1] >> 31) : 0u;
    ends = ((cur << 1) | pb) & ~cur;
    if (tid == NW_LAST) ends &= 0xFFFFu;
    cnt = __popc(ends);
  }
  int v = cnt;
#pragma unroll
  for (int off = 1; off < 64; off <<= 1) {
    const int t = __shfl_up(v, off);
    if (lane >= off) v += t;
  }
  if (lane == 63) wsum[wid] = v;
  __syncthreads();
  if (tid == 0) {
    int s = 0;
#pragma unroll
    for (int w = 0; w < 8; w++) { wbase[w] = s; s += wsum[w]; }
    nruns_sh = s;
  }
  __syncthreads();
  int slot = wbase[wid] + v - cnt;

  if (ends) {
    unsigned m = ends;
    while (m) {
      const int bit = __builtin_ctz(m);
      m &= m - 1;
      const int e = tid * 32 + bit;
      const int eb = e - 1;
      int w = eb >> 5;
      const int bb = eb & 31;
      const unsigned z = bdbits[w] << (31 - bb);
      const unsigned nz = ~z;
      int run = nz ? __builtin_clz(nz) : 32;
      if (run == bb + 1) {
        while (w > 0) {
          w--;
          const unsigned nx = ~bdbits[w];
          const int t2 = nx ? __builtin_clz(nx) : 32;
          run += t2;
          if (t2 < 32) break;
        }
      }
      const int s = e - run;
      float mv = lbuf[s];
      int mi = s;
      for (int i = s + 1; i < e; i++) {
        const float val = lbuf[i];
        if (val > mv) { mv = val; mi = i; }
      }
      runIdx[slot++] = mi;
    }
  }
  __syncthreads();

  const int n = nruns_sh;
  const int nch = (n + CHUNK - 1) / CHUNK;
  for (int f = tid; f < nch * NCLS; f += 512) {
    const int ch = f / NCLS;
    const int cls = f - ch * NCLS;
    const int s = ch * CHUNK;
    const int e = (s + CHUNK < n) ? s + CHUNK : n;
    const int p0 = runIdx[s];
    if (cls == NCLS - 1) chP0[ch] = p0;
    int last = (cls < 18) ? (p0 - 18 + cls) : -1;
    for (int i = s; i < e; i++) {
      int bd = runIdx[i];
      if (last > 0 && bd - last < MIN_GAP_) {
        const int sum = bd + last;
        const int h = sum >> 1;
        bd = (sum & 1) ? (h + (h & 1)) : h;
      }
      last = bd;
    }
    outLast[ch][cls] = last;
  }
  __syncthreads();

  if (wid == 0) {
    int q = -1;
    int row = (lane < NCLS && nch > 0) ? outLast[0][lane] : -1;
    for (int ch = 0; ch < nch; ch++) {
      const int rown = (lane < NCLS && ch + 1 < nch) ? outLast[ch + 1][lane] : -1;
      const int p0 = chP0[ch];
      const int cls = (q > 0 && p0 - q < MIN_GAP_) ? (q - (p0 - 18)) : (NCLS - 1);
      if (lane == 0) inL[ch] = q;
      q = __shfl(row, cls);
      row = rown;
    }
    if (lane == 0) inL[nch] = q;
  }
  __syncthreads();

  for (int ch = tid; ch < nch; ch += 512) {
    const int s = ch * CHUNK;
    const int e = (s + CHUNK < n) ? s + CHUNK : n;
    const int qin = inL[ch];
    const int qout = inL[ch + 1];
    if (qin >= 0 && qin != qout) res[qin] = 1;
    int last = qin;
    for (int i = s; i < e; i++) {
      int bd = runIdx[i];
      if (last > 0 && bd - last < MIN_GAP_) {
        const int sum = bd + last;
        const int h = sum >> 1;
        bd = (sum & 1) ? (h + (h & 1)) : h;
        if (last != qout) res[last] = 0;
      }
      if (bd != qout) res[bd] = 1;
      last = bd;
    }
  }
  if (tid == 0 && n > 0) res[inL[nch]] = 1;
  __syncthreads();

  for (int j = tid; j < TT; j += 512) {
    if (wbuf[j] != 1) continue;
    const int lo = (j - REF_GAP_ < 0) ? 0 : j - REF_GAP_;
    const int hi = (j + REF_GAP_ - 1 > TT - 1) ? TT - 1 : j + REF_GAP_ - 1;
    int seg = 0;
    for (int w = lo; w <= hi; w++) seg += res[w];
    if (seg == 0) {
      res[j] = 1;
    } else if (seg == 1) {
      if (res[j] != 1) {
        for (int w = lo; w <= hi; w++) res[w] = (int)wbuf[w];
      }
    } else {
      int zidx = -1;
      for (int k = 1; k <= REF_GAP_; k++) {
        const int li = (j - k < 0) ? 0 : j - k;
        const int ri = (j + k > TT - 1) ? TT - 1 : j + k;
        if (res[li] == 1 && wbuf[li] != 1) { zidx = li; break; }
        if (res[ri] == 1 && wbuf[ri] != 1) { zidx = ri; break; }
      }
      if (zidx >= 0) res[zidx] = 0;
      res[j] = 1;
    }
  }
  __syncthreads();

  const int L = L_sh;
  for (int t = tid; t < TT; t += 512)
    out2[(size_t)b * TT + t] = (t >= 1 && t < L - 1) ? (float)res[t] : 0.f;
}

extern "C" void kernel_launch(void* const* d_in, const int* in_sizes, int n_in,
                              void* d_out, int out_size, void* d_ws, size_t ws_size,
                              hipStream_t stream) {
  const float* feat        = (const float*)d_in[0];
  const int*   word_bd     = (const int*)d_in[1];
  const float* non_padding = (const float*)d_in[2];
  const float* W           = (const float*)d_in[3];
  const float* bias        = (const float*)d_in[4];

  float* out  = (float*)d_out;
  float* out0 = out;
  float* out1 = out + (size_t)NB * TT;
  float* out2 = out + (size_t)NB * TT + (size_t)NB * TT * (CC - 1);

  unsigned short* Wb = (unsigned short*)d_ws;   // 112*256 bf16 = 57344 B

  hipLaunchKernelGGL(wconv_kernel, dim3(112), dim3(256), 0, stream, W, Wb);
  hipLaunchKernelGGL(gemm_mfma, dim3(NGB), dim3(384), 0, stream,
                     feat, W, bias, Wb, out0, out1);
  hipLaunchKernelGGL(phase_kernel, dim3(NB), dim3(512), 0, stream,
                     out0, word_bd, non_padding, out2);
}

// Round 10
// 73.994 us; speedup vs baseline: 1.1811x; 1.1811x over previous
//
#include <hip/hip_runtime.h>

#define NB 16
#define TT 6000
#define HH 256
#define CC 105
#define MIN_GAP_ 19
#define REF_GAP_ 9

using short8  = __attribute__((ext_vector_type(8))) short;
using short4v = __attribute__((ext_vector_type(4))) short;
using f32x4   = __attribute__((ext_vector_type(4))) float;

static __device__ __forceinline__ short f2bf(float x) {
  unsigned u = __builtin_bit_cast(unsigned, x);
  unsigned r = (u + 0x7FFFu + ((u >> 16) & 1u)) >> 16;   // RNE
  return (short)r;
}

// ---- one-time W (channels 1..104) f32 -> bf16, zero-padded to 112 rows ----
__global__ __launch_bounds__(256) void wconv_kernel(
    const float* __restrict__ W, unsigned short* __restrict__ Wb) {
  const int idx = blockIdx.x * 256 + threadIdx.x;   // 0..28671 (112*256)
  const int c = idx >> 8, k = idx & 255;
  const float v = (c < CC - 1) ? W[(size_t)(c + 1) * HH + k] : 0.f;
  Wb[idx] = (unsigned short)f2bf(v);
}

// ---- GEMM: A coalesced->LDS (64KB, swizzled; 2 blocks/CU), B held entirely
// ---- in registers per wave (ng=wid, 8 x short8 = 32 VGPR). BM=128, 8 waves.
// ---- MFMA loop: 64 ds_read_b128 + 64 MFMA, zero global loads, one barrier.
#define BMR 128

__global__ __launch_bounds__(512, 4) void gemm_mfma(
    const float* __restrict__ feat, const float* __restrict__ W,
    const float* __restrict__ bias, const unsigned short* __restrict__ Wb,
    float* __restrict__ out0, float* __restrict__ out1) {
  __shared__ __align__(16) unsigned short aS[BMR * 256];   // 64 KB, swizzled
  const int tid  = threadIdx.x;
  const int wid  = tid >> 6;        // wave 0..7
  const int lane = tid & 63;
  const int rl   = lane & 15;
  const int kg   = lane >> 4;
  const int row0 = blockIdx.x * BMR;

  // ---- issue A stage loads: wave w owns rows p*8+w, full 1KB coalesced ----
  float4 areg[16];
  {
    const float* fbase = feat + (size_t)(row0 + wid) * HH + lane * 4;
#pragma unroll
    for (int p = 0; p < 16; p++)
      areg[p] = *reinterpret_cast<const float4*>(fbase + (size_t)p * 8 * HH);
  }

  // ---- issue B loads: wave w (<7) holds channel-group w's full K in regs ----
  short8 breg[8];
  if (wid < 7) {
    const unsigned short* wbbase = Wb + ((size_t)(wid * 16 + rl) << 8) + kg * 8;
#pragma unroll
    for (int ks = 0; ks < 8; ks++)
      breg[ks] = *reinterpret_cast<const short8*>(wbbase + ks * 32);
  }

  // ---- stage: ch0 f32 dot (verified R9 order) + bf16 + swizzled ds_write ----
  const float4 w0 = *reinterpret_cast<const float4*>(W + lane * 4);
  const float b0 = bias[0];
#pragma unroll
  for (int p = 0; p < 16; p++) {
    const int lrow = p * 8 + wid;
    const float4 a = areg[p];
    float s = a.x * w0.x;
    s = fmaf(a.y, w0.y, s); s = fmaf(a.z, w0.z, s); s = fmaf(a.w, w0.w, s);
#pragma unroll
    for (int off = 1; off < 64; off <<= 1) s += __shfl_xor(s, off);
    if (lane == 0)
      out0[row0 + lrow] = fminf(fmaxf(s + b0, -16.f), 16.f);
    short4v bf;
    bf[0] = f2bf(a.x); bf[1] = f2bf(a.y); bf[2] = f2bf(a.z); bf[3] = f2bf(a.w);
    const int dst = (lrow << 9) + ((lane * 8) ^ ((lrow & 7) << 4));
    *reinterpret_cast<short4v*>((char*)aS + dst) = bf;
  }
  __syncthreads();

  // ---- MFMA sweep: A from LDS, B resident in registers ----
  if (wid < 7) {
    const int xr = (rl & 7) << 4;
    f32x4 acc[8];
#pragma unroll
    for (int rg = 0; rg < 8; rg++) acc[rg] = (f32x4){0.f, 0.f, 0.f, 0.f};

#pragma unroll
    for (int ks = 0; ks < 8; ks++) {
      const int slot = (ks * 64 + kg * 16) ^ xr;
#pragma unroll
      for (int rg = 0; rg < 8; rg++) {
        const short8 av = *reinterpret_cast<const short8*>(
            (const char*)aS + (((rg * 16 + rl) << 9) + slot));
        acc[rg] = __builtin_amdgcn_mfma_f32_16x16x32_bf16(av, breg[ks], acc[rg], 0, 0, 0);
      }
    }

    // D layout: col = lane&15, row = (lane>>4)*4 + reg  [m89]
    const int c = wid * 16 + rl;
    if (c < CC - 1) {
      const float bb = bias[c + 1];
#pragma unroll
      for (int rg = 0; rg < 8; rg++) {
        const int rbase = row0 + rg * 16 + kg * 4;
#pragma unroll
        for (int r = 0; r < 4; r++)
          out1[(size_t)(rbase + r) * (CC - 1) + c] = acc[rg][r] + bb;
      }
    }
  }
}

// ---- phase: bitwise run detect + chunk-speculative merge + parallel p2 ----
#define NW 192
#define NW_LAST 187
#define CHUNK 32
#define NCLS 19
#define MAXRUNS 3072
#define MAXCH 96

__global__ __launch_bounds__(512) void phase_kernel(
    const float* __restrict__ bd_logits,
    const int* __restrict__ word_bd,
    const float* __restrict__ non_padding,
    float* __restrict__ out2) {
  __shared__ __align__(16) float lbuf[TT];
  __shared__ unsigned char wbuf[TT];
  __shared__ int res[TT];
  __shared__ unsigned bdbits[NW];
  __shared__ int runIdx[MAXRUNS];
  __shared__ int outLast[MAXCH][NCLS + 1];
  __shared__ int chP0[MAXCH];
  __shared__ int inL[MAXCH + 1];
  __shared__ int wsum[8];
  __shared__ int wbase[8];
  __shared__ int L_sh, nruns_sh;

  const int b = blockIdx.x;
  const int tid = threadIdx.x;
  const int lane = tid & 63;
  const int wid = tid >> 6;
  if (tid == 0) L_sh = 0;
  __syncthreads();

  int cnt_np = 0;
#pragma unroll
  for (int k = 0; k < 12; k++) {
    const int j = k * 512 + tid;
    bool pred = false;
    if (j < TT) {
      const float l = bd_logits[(size_t)b * TT + j];
      lbuf[j] = l;
      pred = l > 0.f;
      wbuf[j] = (unsigned char)word_bd[(size_t)b * TT + j];
      res[j] = 0;
      cnt_np += (non_padding[(size_t)b * TT + j] != 0.f) ? 1 : 0;
    }
    const unsigned long long m = __ballot(pred);
    if (lane == 0) {
      const int w0 = (k * 512 + (tid & ~63)) >> 5;
      bdbits[w0]     = (unsigned)m;
      bdbits[w0 + 1] = (unsigned)(m >> 32);
    }
  }
#pragma unroll
  for (int off = 32; off; off >>= 1) cnt_np += __shfl_xor(cnt_np, off);
  if (lane == 0) atomicAdd(&L_sh, cnt_np);
  __syncthreads();

  int cnt = 0;
  unsigned ends = 0;
  if (tid < NW) {
    const unsigned cur = bdbits[tid];
    const unsigned pb = tid ? (bdbits[tid - 1] >> 31) : 0u;
    ends = ((cur << 1) | pb) & ~cur;
    if (tid == NW_LAST) ends &= 0xFFFFu;
    cnt = __popc(ends);
  }
  int v = cnt;
#pragma unroll
  for (int off = 1; off < 64; off <<= 1) {
    const int t = __shfl_up(v, off);
    if (lane >= off) v += t;
  }
  if (lane == 63) wsum[wid] = v;
  __syncthreads();
  if (tid == 0) {
    int s = 0;
#pragma unroll
    for (int w = 0; w < 8; w++) { wbase[w] = s; s += wsum[w]; }
    nruns_sh = s;
  }
  __syncthreads();
  int slot = wbase[wid] + v - cnt;

  if (ends) {
    unsigned m = ends;
    while (m) {
      const int bit = __builtin_ctz(m);
      m &= m - 1;
      const int e = tid * 32 + bit;
      const int eb = e - 1;
      int w = eb >> 5;
      const int bb = eb & 31;
      const unsigned z = bdbits[w] << (31 - bb);
      const unsigned nz = ~z;
      int run = nz ? __builtin_clz(nz) : 32;
      if (run == bb + 1) {
        while (w > 0) {
          w--;
          const unsigned nx = ~bdbits[w];
          const int t2 = nx ? __builtin_clz(nx) : 32;
          run += t2;
          if (t2 < 32) break;
        }
      }
      const int s = e - run;
      float mv = lbuf[s];
      int mi = s;
      for (int i = s + 1; i < e; i++) {
        const float val = lbuf[i];
        if (val > mv) { mv = val; mi = i; }
      }
      runIdx[slot++] = mi;
    }
  }
  __syncthreads();

  const int n = nruns_sh;
  const int nch = (n + CHUNK - 1) / CHUNK;
  for (int f = tid; f < nch * NCLS; f += 512) {
    const int ch = f / NCLS;
    const int cls = f - ch * NCLS;
    const int s = ch * CHUNK;
    const int e = (s + CHUNK < n) ? s + CHUNK : n;
    const int p0 = runIdx[s];
    if (cls == NCLS - 1) chP0[ch] = p0;
    int last = (cls < 18) ? (p0 - 18 + cls) : -1;
    for (int i = s; i < e; i++) {
      int bd = runIdx[i];
      if (last > 0 && bd - last < MIN_GAP_) {
        const int sum = bd + last;
        const int h = sum >> 1;
        bd = (sum & 1) ? (h + (h & 1)) : h;
      }
      last = bd;
    }
    outLast[ch][cls] = last;
  }
  __syncthreads();

  if (wid == 0) {
    int q = -1;
    int row = (lane < NCLS && nch > 0) ? outLast[0][lane] : -1;
    for (int ch = 0; ch < nch; ch++) {
      const int rown = (lane < NCLS && ch + 1 < nch) ? outLast[ch + 1][lane] : -1;
      const int p0 = chP0[ch];
      const int cls = (q > 0 && p0 - q < MIN_GAP_) ? (q - (p0 - 18)) : (NCLS - 1);
      if (lane == 0) inL[ch] = q;
      q = __shfl(row, cls);
      row = rown;
    }
    if (lane == 0) inL[nch] = q;
  }
  __syncthreads();

  for (int ch = tid; ch < nch; ch += 512) {
    const int s = ch * CHUNK;
    const int e = (s + CHUNK < n) ? s + CHUNK : n;
    const int qin = inL[ch];
    const int qout = inL[ch + 1];
    if (qin >= 0 && qin != qout) res[qin] = 1;
    int last = qin;
    for (int i = s; i < e; i++) {
      int bd = runIdx[i];
      if (last > 0 && bd - last < MIN_GAP_) {
        const int sum = bd + last;
        const int h = sum >> 1;
        bd = (sum & 1) ? (h + (h & 1)) : h;
        if (last != qout) res[last] = 0;
      }
      if (bd != qout) res[bd] = 1;
      last = bd;
    }
  }
  if (tid == 0 && n > 0) res[inL[nch]] = 1;
  __syncthreads();

  for (int j = tid; j < TT; j += 512) {
    if (wbuf[j] != 1) continue;
    const int lo = (j - REF_GAP_ < 0) ? 0 : j - REF_GAP_;
    const int hi = (j + REF_GAP_ - 1 > TT - 1) ? TT - 1 : j + REF_GAP_ - 1;
    int seg = 0;
    for (int w = lo; w <= hi; w++) seg += res[w];
    if (seg == 0) {
      res[j] = 1;
    } else if (seg == 1) {
      if (res[j] != 1) {
        for (int w = lo; w <= hi; w++) res[w] = (int)wbuf[w];
      }
    } else {
      int zidx = -1;
      for (int k = 1; k <= REF_GAP_; k++) {
        const int li = (j - k < 0) ? 0 : j - k;
        const int ri = (j + k > TT - 1) ? TT - 1 : j + k;
        if (res[li] == 1 && wbuf[li] != 1) { zidx = li; break; }
        if (res[ri] == 1 && wbuf[ri] != 1) { zidx = ri; break; }
      }
      if (zidx >= 0) res[zidx] = 0;
      res[j] = 1;
    }
  }
  __syncthreads();

  const int L = L_sh;
  for (int t = tid; t < TT; t += 512)
    out2[(size_t)b * TT + t] = (t >= 1 && t < L - 1) ? (float)res[t] : 0.f;
}

extern "C" void kernel_launch(void* const* d_in, const int* in_sizes, int n_in,
                              void* d_out, int out_size, void* d_ws, size_t ws_size,
                              hipStream_t stream) {
  const float* feat        = (const float*)d_in[0];
  const int*   word_bd     = (const int*)d_in[1];
  const float* non_padding = (const float*)d_in[2];
  const float* W           = (const float*)d_in[3];
  const float* bias        = (const float*)d_in[4];

  float* out  = (float*)d_out;
  float* out0 = out;
  float* out1 = out + (size_t)NB * TT;
  float* out2 = out + (size_t)NB * TT + (size_t)NB * TT * (CC - 1);

  unsigned short* Wb = (unsigned short*)d_ws;   // 112*256 bf16 = 57344 B

  hipLaunchKernelGGL(wconv_kernel, dim3(112), dim3(256), 0, stream, W, Wb);
  hipLaunchKernelGGL(gemm_mfma, dim3((NB * TT) / BMR), dim3(512), 0, stream,
                     feat, W, bias, Wb, out0, out1);
  hipLaunchKernelGGL(phase_kernel, dim3(NB), dim3(512), 0, stream,
                     out0, word_bd, non_padding, out2);
}